// Round 1
// baseline (533.697 us; speedup 1.0000x reference)
//
#include <hip/hip_runtime.h>

// Problem constants (fixed by the reference file)
#define B_   32
#define Q_   512
#define R_   1024
#define D_   2048
#define L_   1536          // Q + R
#define NROW (B_ * 1025)   // rows l in [Q-1, L-1] per batch = 1025 rows -> 32800

// Output layout (tuple flattened in return order, all as float32)
#define O_VALUES 0
#define O_VPM    32768
#define O_VLP    65536
#define O_SC     65568
#define O_RLP    65600
#define O_KL     65632
#define O_KLR    98400
#define O_ADV    131168
#define O_RET    163936

__constant__ float kGamma = 0.99f;
__constant__ float kLmbda = 0.95f;

// ---------------------------------------------------------------------------
// K1: fused dual GEMV. For each needed row l = 511+i (i in [0,1024]) of each
// batch, compute dot(hidden[b,l,:], w_base) and dot(hidden[b,l,:], w_base+w_adapter).
// One wave per row, 64 lanes x 32 floats (8 float4 each). Weights live in
// registers (lane's 32 elements are the same for every row).
// ---------------------------------------------------------------------------
__global__ __launch_bounds__(256) void k_dots(
    const float* __restrict__ hidden,
    const float* __restrict__ wb,
    const float* __restrict__ wa,
    float* __restrict__ vals_dot,     // NROW floats: dot with (w_base+w_adapter)
    float* __restrict__ scores_dot)   // NROW floats: dot with w_base
{
    const int lane = threadIdx.x & 63;
    const int wid  = blockIdx.x * 4 + (threadIdx.x >> 6);
    const int nw   = gridDim.x * 4;

    const float4* wb4 = (const float4*)wb;
    const float4* wa4 = (const float4*)wa;
    float4 vb[8], vs[8];
#pragma unroll
    for (int k = 0; k < 8; ++k) {
        float4 bv = wb4[lane + 64 * k];
        float4 av = wa4[lane + 64 * k];
        vb[k] = bv;
        vs[k] = make_float4(bv.x + av.x, bv.y + av.y, bv.z + av.z, bv.w + av.w);
    }

    for (int row = wid; row < NROW; row += nw) {
        const int bb = row / 1025;
        const int i  = row - bb * 1025;
        const float4* hp =
            (const float4*)(hidden + ((size_t)bb * L_ + 511 + i) * (size_t)D_);
        float4 h[8];
#pragma unroll
        for (int k = 0; k < 8; ++k) h[k] = hp[lane + 64 * k];
        float db = 0.f, ds = 0.f;
#pragma unroll
        for (int k = 0; k < 8; ++k) {
            db += h[k].x * vb[k].x + h[k].y * vb[k].y + h[k].z * vb[k].z + h[k].w * vb[k].w;
            ds += h[k].x * vs[k].x + h[k].y * vs[k].y + h[k].z * vs[k].z + h[k].w * vs[k].w;
        }
#pragma unroll
        for (int d = 32; d > 0; d >>= 1) {
            db += __shfl_down(db, d, 64);
            ds += __shfl_down(ds, d, 64);
        }
        if (lane == 0) { vals_dot[row] = ds; scores_dot[row] = db; }
    }
}

// ---------------------------------------------------------------------------
// K2: per-batch sequential logic. One wave per batch. Lane owns t in
// [lane*16, lane*16+16). GAE via chunked weighted suffix scan.
// ---------------------------------------------------------------------------
__global__ __launch_bounds__(64) void k_seq(
    const float* __restrict__ vals_dot,
    const float* __restrict__ scores_dot,
    const float* __restrict__ gen,
    const float* __restrict__ ref,
    const void* __restrict__ maskraw,
    float* __restrict__ out,
    double* __restrict__ acc,     // [sum_x, sum_x2, n]
    int* __restrict__ flag)       // 1 if mask stored as bytes, 0 if int32
{
    const int b    = blockIdx.x;
    const int lane = threadIdx.x;

    // --- detect mask storage (byte bool vs int32). Reading 8192 uint32s is
    // in-bounds under both layouts. int32 bools are 0/1 -> high 3 bytes always
    // zero; byte bools put a '1' at a misaligned byte for any row len<1024.
    bool oddNZ = false;
    const unsigned int* mu = (const unsigned int*)maskraw;
    for (int j = lane; j < (B_ * R_) / 4; j += 64) {
        if (mu[j] & 0xFFFFFF00u) oddNZ = true;
    }
    const bool byteMode = (__ballot(oddNZ) != 0ull);
    if (b == 0 && lane == 0) *flag = byteMode ? 1 : 0;

    // --- load this lane's mask chunk
    const int base = b * R_ + lane * 16;
    bool m[16];
    if (byteMode) {
        const unsigned char* mb = (const unsigned char*)maskraw;
#pragma unroll
        for (int j = 0; j < 16; ++j) m[j] = mb[base + j] != 0;
    } else {
        const int* mi = (const int*)maskraw;
#pragma unroll
        for (int j = 0; j < 16; ++j) m[j] = mi[base + j] != 0;
    }

    // --- response_last_pos = last index with mask==False; any-pad flag
    int  ll   = -1;
    bool anyT = false;
#pragma unroll
    for (int j = 0; j < 16; ++j) {
        if (!m[j]) ll = lane * 16 + j;
        anyT |= m[j];
    }
#pragma unroll
    for (int d = 1; d < 64; d <<= 1) {
        int o = __shfl_xor(ll, d, 64);
        ll = ll > o ? ll : o;
    }
    int rlp = ll < 0 ? 0 : ll;
    const bool anyPad = (__ballot(anyT) != 0ull);
    const float score = (!anyPad) ? -3.0f : scores_dot[b * 1025 + rlp + 1];
    const int vlp = (rlp > 0 && rlp < R_ - 1) ? rlp + 1 : rlp;  // MAX_RESPONSE_LEN==R

    // --- masked values + value_pad_mask outputs
    float v[16];
#pragma unroll
    for (int j = 0; j < 16; ++j) {
        const int t = lane * 16 + j;
        const bool vpm = m[j] && (t != vlp);
        const float vv = vpm ? 0.f : vals_dot[b * 1025 + t];
        v[j] = vv;
        out[O_VALUES + b * R_ + t] = vv;
        out[O_VPM + b * R_ + t]    = vpm ? 1.f : 0.f;
    }
    float tshf = __shfl_down(v[0], 1, 64);
    const float vnext_head = (lane == 63) ? 0.f : tshf;

    // --- kl, kl_rewards, rewards, GAE deltas
    const float c = kGamma * kLmbda;
    float dl[16];
#pragma unroll
    for (int j = 0; j < 16; ++j) {
        const int t = lane * 16 + j;
        const float kl = gen[b * R_ + t] - ref[b * R_ + t];
        out[O_KL + b * R_ + t]  = kl;
        const float klr = -0.1f * kl;
        out[O_KLR + b * R_ + t] = klr;
        const float rw = klr + ((t == vlp) ? score : 0.f);
        const float vn = (j < 15) ? v[j + 1] : vnext_head;
        dl[j] = rw + kGamma * vn - v[j];
    }

    // --- local reverse scan with zero carry
    float a[16];
    a[15] = dl[15];
#pragma unroll
    for (int j = 14; j >= 0; --j) a[j] = dl[j] + c * a[j + 1];

    // --- cross-lane weighted suffix scan of chunk heads: H_i = sum_{j>=i} (c^16)^(j-i) h_j
    const float c2 = c * c, c4 = c2 * c2, c8 = c4 * c4, c16 = c8 * c8;
    float S = a[0];
    float f = c16;
#pragma unroll
    for (int d = 1; d < 64; d <<= 1) {
        float up = __shfl_down(S, d, 64);
        up = (lane + d < 64) ? up : 0.f;
        S += f * up;
        f *= f;
    }
    float t1 = __shfl_down(S, 1, 64);
    float carry = (lane == 63) ? 0.f : t1;     // true adv at next chunk head
#pragma unroll
    for (int j = 15; j >= 0; --j) {
        a[j] = dl[j] + c * carry;
        carry = a[j];
    }

    // --- outputs: raw advantages (whitened later in-place), returns; whiten partials
    double sx = 0.0, sx2 = 0.0, n = 0.0;
#pragma unroll
    for (int j = 0; j < 16; ++j) {
        const int t = lane * 16 + j;
        out[O_ADV + b * R_ + t] = a[j];
        out[O_RET + b * R_ + t] = a[j] + v[j];
        if (!m[j]) { sx += (double)a[j]; sx2 += (double)a[j] * (double)a[j]; n += 1.0; }
    }
#pragma unroll
    for (int d = 1; d < 64; d <<= 1) {
        sx  += __shfl_xor(sx, d, 64);
        sx2 += __shfl_xor(sx2, d, 64);
        n   += __shfl_xor(n, d, 64);
    }
    if (lane == 0) {
        atomicAdd(&acc[0], sx);
        atomicAdd(&acc[1], sx2);
        atomicAdd(&acc[2], n);
        out[O_VLP + b] = (float)vlp;
        out[O_SC + b]  = score;
        out[O_RLP + b] = (float)rlp;
    }
}

// ---------------------------------------------------------------------------
// K3: masked whitening of advantages, in place on d_out.
// ---------------------------------------------------------------------------
__global__ __launch_bounds__(256) void k_whiten(
    float* __restrict__ out,
    const double* __restrict__ acc,
    const void* __restrict__ maskraw,
    const int* __restrict__ flag)
{
    const int i = blockIdx.x * blockDim.x + threadIdx.x;
    if (i >= B_ * R_) return;
    const double sx = acc[0], sx2 = acc[1], n = acc[2];
    const double mean = sx / n;
    const double var  = (sx2 - sx * sx / n) / (n - 1.0);
    const float  rs   = (float)(1.0 / sqrt(var + 1e-8));
    bool pad;
    if (*flag) pad = ((const unsigned char*)maskraw)[i] != 0;
    else       pad = ((const int*)maskraw)[i] != 0;
    const float x = out[O_ADV + i];
    out[O_ADV + i] = pad ? 0.f : (x - (float)mean) * rs;
}

extern "C" void kernel_launch(void* const* d_in, const int* in_sizes, int n_in,
                              void* d_out, int out_size, void* d_ws, size_t ws_size,
                              hipStream_t stream) {
    const float* hidden = (const float*)d_in[0];
    const float* wb     = (const float*)d_in[1];
    const float* wa     = (const float*)d_in[2];
    const float* gen    = (const float*)d_in[3];
    const float* ref    = (const float*)d_in[4];
    const void*  mask   = d_in[5];
    // d_in[6] = queries_len (constant 512, baked in)

    float* out = (float*)d_out;
    float* wsf = (float*)d_ws;
    float* vals_dot   = wsf;
    float* scores_dot = wsf + NROW;
    double* acc = (double*)((char*)d_ws + (size_t)2 * NROW * sizeof(float)); // byte 262400, 8-aligned
    int* flag   = (int*)((char*)d_ws + (size_t)2 * NROW * sizeof(float) + 3 * sizeof(double));

    hipMemsetAsync((char*)d_ws + (size_t)2 * NROW * sizeof(float), 0,
                   3 * sizeof(double) + sizeof(int), stream);

    hipLaunchKernelGGL(k_dots, dim3(2048), dim3(256), 0, stream,
                       hidden, wb, wa, vals_dot, scores_dot);
    hipLaunchKernelGGL(k_seq, dim3(B_), dim3(64), 0, stream,
                       vals_dot, scores_dot, gen, ref, mask, out, acc, flag);
    hipLaunchKernelGGL(k_whiten, dim3((B_ * R_ + 255) / 256), dim3(256), 0, stream,
                       out, acc, mask, flag);
}